// Round 8
// baseline (90.703 us; speedup 1.0000x reference)
//
#include <hip/hip_runtime.h>
#include <stdint.h>

typedef _Float16 f16x8 __attribute__((ext_vector_type(8)));
typedef __fp16   hf16x2 __attribute__((ext_vector_type(2)));
typedef float    f32x4 __attribute__((ext_vector_type(4)));
typedef uint4    u128a __attribute__((may_alias));

union HU   { uint32_t u; _Float16 h[2]; };
union B128 { uint4 q; f16x8 v; uint32_t d[4]; };
union PKU  { hf16x2 v; uint32_t u; };

__device__ __forceinline__ uint32_t pkrtz(float lo, float hi) {
  PKU u; u.v = __builtin_amdgcn_cvt_pkrtz(lo, hi);
  return u.u;
}

__device__ __forceinline__ float fast_exp2(float x) {
#if __has_builtin(__builtin_amdgcn_exp2f)
  return __builtin_amdgcn_exp2f(x);
#else
  return exp2f(x);
#endif
}
__device__ __forceinline__ float fast_rcp(float x) {
#if __has_builtin(__builtin_amdgcn_rcpf)
  return __builtin_amdgcn_rcpf(x);
#else
  return 1.0f / x;
#endif
}

// Degree-4 Taylor jet of tanh. ×4 of sech² folded into the exp2 argument:
// e4 = 4·e^{2u0} = 2^{2·log2e·u0 + 2};  e+1 = 0.25·e4 + 1;  v0 = e4·r².
__device__ __forceinline__ void tanh_jets(float u0, float u1, float u2, float u3, float u4,
                                          float& t0, float& t1, float& t2, float& t3, float& t4) {
  float aa = fminf(fmaf(2.8853900817779268f, u0, 2.0f), 127.0f);
  float e4 = fast_exp2(aa);                    // 4·e^{2u0}, no overflow (≤2^127)
  float r  = fast_rcp(fmaf(0.25f, e4, 1.0f));  // 1/(e+1)
  t0 = fmaf(-2.0f, r, 1.0f);                   // tanh(u0)
  float v0 = e4 * (r * r);                     // sech²(u0)
  t1 = v0 * u1;
  float h1 = t0 * t1;                          // v1 = -2·h1
  t2 = fmaf(u2, v0, -(u1 * h1));
  float v2 = -fmaf(t0 + t0, t2, t1 * t1);
  t3 = fmaf(u3, v0, fmaf(-1.3333333333f * u2, h1, 0.3333333333f * u1 * v2));
  float v3 = -2.0f * fmaf(t0, t3, t1 * t2);
  t4 = fmaf(u4, v0, fmaf(-1.5f * u3, h1, fmaf(0.5f * u2, v2, 0.25f * u1 * v3)));
}

// ws layout (dwords). MFMA slot identity: (lane-group g = l>>4, half j, k-half s).
// A-frag for tile tm, half s: lane l supplies row mm = 16*tm + (l&15),
// half j = W[k_logical(g,j,s)][mm]; k-permutations match the register-resident
// B-side of each layer:
//   L2: k2(g,j,s) = 16g + 8s + j
//   L3: k3(g,j,s) = 32s + 16*(j>>2) + 4g + (j&3)
//   [0    .. 511 ]  P1: [h][8] floats = {W1[0][h],W1[1][h],W1[2][h],W1[3][h],b1[h],0,0,0}
//   [512  .. 2559]  W2 A-frags (frag fi = tm*2+s, lane l, dword pj)
//   [2560 .. 4607]  W3 A-frags (same shape, k3 permutation)
//   [4608 .. 4671]  W4 as plain f32[64]
__global__ void prep_kernel(const float* __restrict__ W1, const float* __restrict__ b1,
                            const float* __restrict__ W2, const float* __restrict__ W3,
                            const float* __restrict__ W4, uint32_t* __restrict__ ws) {
  const int t = threadIdx.x;  // 256 threads, 1 block
  float* P1 = (float*)ws;
  if (t < 64) {
    P1[t * 8 + 0] = W1[0 * 64 + t];
    P1[t * 8 + 1] = W1[1 * 64 + t];
    P1[t * 8 + 2] = W1[2 * 64 + t];
    P1[t * 8 + 3] = W1[3 * 64 + t];
    P1[t * 8 + 4] = b1[t];
    P1[t * 8 + 5] = 0.f; P1[t * 8 + 6] = 0.f; P1[t * 8 + 7] = 0.f;
  }
  for (int idx = t; idx < 2048; idx += 256) {
    const int fi = idx >> 8;            // frag index 0..7 = tm*2 + s
    const int tm = fi >> 1, s = fi & 1;
    const int l  = (idx >> 2) & 63;     // lane
    const int pj = idx & 3;             // dword: halves j0=2pj, j0+1
    const int g  = l >> 4;
    const int mm = 16 * tm + (l & 15);  // h_out row
    const int j0 = 2 * pj, j1 = 2 * pj + 1;
    const int k2a = 16 * g + 8 * s + j0;
    const int k2b = 16 * g + 8 * s + j1;
    HU a; a.h[0] = (_Float16)W2[k2a * 64 + mm]; a.h[1] = (_Float16)W2[k2b * 64 + mm];
    ws[512 + idx] = a.u;
    const int k3a = 32 * s + 16 * (j0 >> 2) + 4 * g + (j0 & 3);
    const int k3b = 32 * s + 16 * (j1 >> 2) + 4 * g + (j1 & 3);
    HU b; b.h[0] = (_Float16)W3[k3a * 64 + mm]; b.h[1] = (_Float16)W3[k3b * 64 + mm];
    ws[2560 + idx] = b.u;
  }
  if (t < 64) {
    ws[4608 + t] = __float_as_uint(W4[t]);
  }
}

#define MFMA16(A, B, C) __builtin_amdgcn_mfma_f32_16x16x32_f16((A), (B), (C), 0, 0, 0)

__global__ __launch_bounds__(256, 4)
void beam_kernel(const float* __restrict__ X, const float* __restrict__ Ein,
                 const float* __restrict__ Iin, const float* __restrict__ Qin,
                 const float* __restrict__ b2, const float* __restrict__ b3,
                 const float* __restrict__ b4, const uint32_t* __restrict__ ws,
                 float* __restrict__ out, int n) {
  const int tid = threadIdx.x;
  const int w   = tid >> 6;
  const int l   = tid & 63;
  const int g   = l >> 4;
  const int p   = l & 15;
  int i = (blockIdx.x * 4 + w) * 16 + p;
  if (i >= n) i = n - 1;

  const float x  = X[i];
  const float Ev = Ein[i], Iv = Iin[i], qv = Qin[i];
  const float f1 = Ev * 5.0e-12f;   // E / 2e11
  const float f2 = Iv * 1.0e6f;     // I / 1e-6
  const float f3 = qv * 1.0e-3f;    // q / 1e3
  const float sf = qv * fast_rcp(fmaf(Ev, Iv, 1.1920929e-7f));  // q/(E*I+eps)

  const float* P1f = (const float*)ws;
  const float* W4f = (const float*)(ws + 4608);

  // ---- Layer 1: lane (g,p) computes h = 16g + hh for point p; jets for the
  //      pair (hh=2hp, 2hp+1) packed straight into L2 B-frag dwords via pkrtz ----
  uint32_t dw2[5][2][4];
  #pragma unroll
  for (int hp = 0; hp < 8; ++hp) {
    const int s = hp >> 2, di = hp & 3;
    const int h0 = 16 * g + 2 * hp;
    float A0, A1, A2, A3, A4, B0, B1, B2, B3, B4;
    {
      const float4 wv = *(const float4*)(P1f + h0 * 8);
      const float bb  = P1f[h0 * 8 + 4];
      float u0 = fmaf(wv.x, x, fmaf(wv.y, f1, fmaf(wv.z, f2, fmaf(wv.w, f3, bb))));
      tanh_jets(u0, wv.x, 0.f, 0.f, 0.f, A0, A1, A2, A3, A4);
    }
    {
      const float4 wv = *(const float4*)(P1f + (h0 + 1) * 8);
      const float bb  = P1f[(h0 + 1) * 8 + 4];
      float u0 = fmaf(wv.x, x, fmaf(wv.y, f1, fmaf(wv.z, f2, fmaf(wv.w, f3, bb))));
      tanh_jets(u0, wv.x, 0.f, 0.f, 0.f, B0, B1, B2, B3, B4);
    }
    dw2[0][s][di] = pkrtz(A0, B0);
    dw2[1][s][di] = pkrtz(A1, B1);
    dw2[2][s][di] = pkrtz(A2, B2);
    dw2[3][s][di] = pkrtz(A3, B3);
    dw2[4][s][di] = pkrtz(A4, B4);
  }
  f16x8 bf2[5][2];
  #pragma unroll
  for (int k = 0; k < 5; ++k)
    #pragma unroll
    for (int s = 0; s < 2; ++s) {
      B128 t; t.d[0] = dw2[k][s][0]; t.d[1] = dw2[k][s][1];
      t.d[2] = dw2[k][s][2]; t.d[3] = dw2[k][s][3];
      bf2[k][s] = t.v;
    }

  // ---- Layer 2 (MFMA): C: col = p, row h_out = 16tm + 4g + r ----
  f32x4 acc[5][4];
  #pragma unroll
  for (int tm = 0; tm < 4; ++tm) {
    const float4 bv = *(const float4*)(b2 + 16 * tm + 4 * g);
    acc[0][tm] = (f32x4){bv.x, bv.y, bv.z, bv.w};
    #pragma unroll
    for (int k = 1; k < 5; ++k) acc[k][tm] = (f32x4){0.f, 0.f, 0.f, 0.f};
  }
  #pragma unroll
  for (int s = 0; s < 2; ++s) {
    #pragma unroll
    for (int tm = 0; tm < 4; ++tm) {
      B128 af; af.q = *(const u128a*)(ws + 512 + ((tm * 2 + s) * 64 + l) * 4);
      #pragma unroll
      for (int k = 0; k < 5; ++k)
        acc[k][tm] = MFMA16(af.v, bf2[k][s], acc[k][tm]);
    }
  }

  // ---- tanh jets; pack straight into L3 B-frags: slot (s=tm>>1, j=4(tm&1)+r) ----
  uint32_t dw3[5][2][4];
  #pragma unroll
  for (int tm = 0; tm < 4; ++tm) {
    const int s = tm >> 1, db = 2 * (tm & 1);
    float A0, A1, A2, A3, A4, B0, B1, B2, B3, B4;
    tanh_jets(acc[0][tm][0], acc[1][tm][0], acc[2][tm][0], acc[3][tm][0], acc[4][tm][0],
              A0, A1, A2, A3, A4);
    tanh_jets(acc[0][tm][1], acc[1][tm][1], acc[2][tm][1], acc[3][tm][1], acc[4][tm][1],
              B0, B1, B2, B3, B4);
    dw3[0][s][db] = pkrtz(A0, B0);
    dw3[1][s][db] = pkrtz(A1, B1);
    dw3[2][s][db] = pkrtz(A2, B2);
    dw3[3][s][db] = pkrtz(A3, B3);
    dw3[4][s][db] = pkrtz(A4, B4);
    tanh_jets(acc[0][tm][2], acc[1][tm][2], acc[2][tm][2], acc[3][tm][2], acc[4][tm][2],
              A0, A1, A2, A3, A4);
    tanh_jets(acc[0][tm][3], acc[1][tm][3], acc[2][tm][3], acc[3][tm][3], acc[4][tm][3],
              B0, B1, B2, B3, B4);
    dw3[0][s][db + 1] = pkrtz(A0, B0);
    dw3[1][s][db + 1] = pkrtz(A1, B1);
    dw3[2][s][db + 1] = pkrtz(A2, B2);
    dw3[3][s][db + 1] = pkrtz(A3, B3);
    dw3[4][s][db + 1] = pkrtz(A4, B4);
  }
  f16x8 bf3[5][2];
  #pragma unroll
  for (int k = 0; k < 5; ++k)
    #pragma unroll
    for (int s = 0; s < 2; ++s) {
      B128 t; t.d[0] = dw3[k][s][0]; t.d[1] = dw3[k][s][1];
      t.d[2] = dw3[k][s][2]; t.d[3] = dw3[k][s][3];
      bf3[k][s] = t.v;
    }

  // ---- Layer 3 (MFMA) ----
  #pragma unroll
  for (int tm = 0; tm < 4; ++tm) {
    const float4 bv = *(const float4*)(b3 + 16 * tm + 4 * g);
    acc[0][tm] = (f32x4){bv.x, bv.y, bv.z, bv.w};
    #pragma unroll
    for (int k = 1; k < 5; ++k) acc[k][tm] = (f32x4){0.f, 0.f, 0.f, 0.f};
  }
  #pragma unroll
  for (int s = 0; s < 2; ++s) {
    #pragma unroll
    for (int tm = 0; tm < 4; ++tm) {
      B128 af; af.q = *(const u128a*)(ws + 2560 + ((tm * 2 + s) * 64 + l) * 4);
      #pragma unroll
      for (int k = 0; k < 5; ++k)
        acc[k][tm] = MFMA16(af.v, bf3[k][s], acc[k][tm]);
    }
  }

  // ---- tanh jets in place (f32; feeds L4 at full precision) ----
  #pragma unroll
  for (int tm = 0; tm < 4; ++tm) {
    #pragma unroll
    for (int r = 0; r < 4; ++r) {
      float t0, t1, t2, t3, t4;
      tanh_jets(acc[0][tm][r], acc[1][tm][r], acc[2][tm][r], acc[3][tm][r], acc[4][tm][r],
                t0, t1, t2, t3, t4);
      acc[0][tm][r] = t0; acc[1][tm][r] = t1; acc[2][tm][r] = t2;
      acc[3][tm][r] = t3; acc[4][tm][r] = t4;
    }
  }

  // ---- Layer 4 (64 -> 1): per-lane partial over h = 16tm+4g+r, then
  //      butterfly-reduce across the 4 lanes sharing point p ----
  float zz[5] = {0.f, 0.f, 0.f, 0.f, 0.f};
  #pragma unroll
  for (int tm = 0; tm < 4; ++tm) {
    const float4 wv = *(const float4*)(W4f + 16 * tm + 4 * g);
    #pragma unroll
    for (int k = 0; k < 5; ++k) {
      zz[k] = fmaf(wv.x, acc[k][tm][0], zz[k]);
      zz[k] = fmaf(wv.y, acc[k][tm][1], zz[k]);
      zz[k] = fmaf(wv.z, acc[k][tm][2], zz[k]);
      zz[k] = fmaf(wv.w, acc[k][tm][3], zz[k]);
    }
  }
  #pragma unroll
  for (int k = 0; k < 5; ++k) {
    zz[k] += __shfl_xor(zz[k], 16, 64);
    zz[k] += __shfl_xor(zz[k], 32, 64);
  }

  if (l < 16) {
    const float psi   = zz[0] + b4[0];
    const float px    = zz[1];
    const float pxx   = 2.0f  * zz[2];
    const float pxxx  = 6.0f  * zz[3];
    const float pxxxx = 24.0f * zz[4];
    const float x2 = x * x;
    out[0 * n + i] = sf * (x2 * psi);
    out[1 * n + i] = sf * fmaf(2.0f * x, psi, x2 * px);
    out[2 * n + i] = sf * (fmaf(4.0f * x, px, 2.0f * psi) + x2 * pxx);
    out[3 * n + i] = sf * (fmaf(6.0f * x, pxx, 6.0f * px) + x2 * pxxx);
    out[4 * n + i] = sf * (fmaf(8.0f * x, pxxx, 12.0f * pxx) + x2 * pxxxx);
  }
}

extern "C" void kernel_launch(void* const* d_in, const int* in_sizes, int n_in,
                              void* d_out, int out_size, void* d_ws, size_t ws_size,
                              hipStream_t stream) {
  const float* X  = (const float*)d_in[0];
  const float* E  = (const float*)d_in[1];
  const float* I  = (const float*)d_in[2];
  const float* q  = (const float*)d_in[3];
  const float* W1 = (const float*)d_in[4];
  const float* b1 = (const float*)d_in[5];
  const float* W2 = (const float*)d_in[6];
  const float* b2 = (const float*)d_in[7];
  const float* W3 = (const float*)d_in[8];
  const float* b3 = (const float*)d_in[9];
  const float* W4 = (const float*)d_in[10];
  const float* b4 = (const float*)d_in[11];
  const int n = in_sizes[0];
  uint32_t* ws = (uint32_t*)d_ws;
  float* out = (float*)d_out;

  prep_kernel<<<dim3(1), dim3(256), 0, stream>>>(W1, b1, W2, W3, W4, ws);
  // block = 256 threads = 4 waves; each wave = 16 points -> 64 points/block
  beam_kernel<<<dim3((n + 63) / 64), dim3(256), 0, stream>>>(X, E, I, q, b2, b3, b4, ws, out, n);
}

// Round 9
// 70.287 us; speedup vs baseline: 1.2905x; 1.2905x over previous
//
#include <hip/hip_runtime.h>
#include <stdint.h>

typedef _Float16 f16x2 __attribute__((ext_vector_type(2)));
typedef _Float16 f16x8 __attribute__((ext_vector_type(8)));
typedef __fp16   hf16x2 __attribute__((ext_vector_type(2)));
typedef float    f32x4 __attribute__((ext_vector_type(4)));
typedef uint4    u128a __attribute__((may_alias));

union HU   { uint32_t u; _Float16 h[2]; };
union B128 { uint4 q; f16x8 v; uint32_t d[4]; f16x2 p2[4]; };
union PKU  { hf16x2 v; uint32_t u; };

__device__ __forceinline__ uint32_t pkrtz(float lo, float hi) {
  PKU u; u.v = __builtin_amdgcn_cvt_pkrtz(lo, hi);
  return u.u;
}

__device__ __forceinline__ float fdot2f(f16x2 a, f16x2 b, float c) {
#if __has_builtin(__builtin_amdgcn_fdot2)
  return __builtin_amdgcn_fdot2(a, b, c, false);
#else
  return fmaf((float)a[1], (float)b[1], fmaf((float)a[0], (float)b[0], c));
#endif
}

__device__ __forceinline__ float fast_exp2(float x) {
#if __has_builtin(__builtin_amdgcn_exp2f)
  return __builtin_amdgcn_exp2f(x);
#else
  return exp2f(x);
#endif
}
__device__ __forceinline__ float fast_rcp(float x) {
#if __has_builtin(__builtin_amdgcn_rcpf)
  return __builtin_amdgcn_rcpf(x);
#else
  return 1.0f / x;
#endif
}

// Degree-4 Taylor jet of tanh. ×4 of sech² folded into the exp2 argument.
__device__ __forceinline__ void tanh_jets(float u0, float u1, float u2, float u3, float u4,
                                          float& t0, float& t1, float& t2, float& t3, float& t4) {
  float aa = fminf(fmaf(2.8853900817779268f, u0, 2.0f), 127.0f);
  float e4 = fast_exp2(aa);                    // 4·e^{2u0}
  float r  = fast_rcp(fmaf(0.25f, e4, 1.0f));  // 1/(e+1)
  t0 = fmaf(-2.0f, r, 1.0f);                   // tanh(u0)
  float v0 = e4 * (r * r);                     // sech²(u0)
  t1 = v0 * u1;
  float h1 = t0 * t1;                          // v1 = -2·h1
  t2 = fmaf(u2, v0, -(u1 * h1));
  float v2 = -fmaf(t0 + t0, t2, t1 * t1);
  t3 = fmaf(u3, v0, fmaf(-1.3333333333f * u2, h1, 0.3333333333f * u1 * v2));
  float v3 = -2.0f * fmaf(t0, t3, t1 * t2);
  t4 = fmaf(u4, v0, fmaf(-1.5f * u3, h1, fmaf(0.5f * u2, v2, 0.25f * u1 * v3)));
}

// ws layout (dwords). MFMA slot identity: (lane-group g = l>>4, half j, k-half s).
// A-frag tile tm, half s: lane l = row mm = 16*tm + (l&15); half j = W[k(g,j,s)][mm].
//   L2 weights use k2(g,j,s) = 16g + 8s + j          (matches L1's fill order)
//   L3 weights use k3(g,j,s) = 32s + 16*(j>>2) + 4g + (j&3)   (matches pack order)
//   [0    .. 511 ]  P1: [h][8] floats = {W1[0][h],W1[1][h],W1[2][h],W1[3][h],b1[h],0,0,0}
//   [512  .. 2559]  W2 A-frags (frag fi = tm*2+s, lane l, dword pj)
//   [2560 .. 4607]  W3 A-frags (same shape, k3 permutation)
//   [4608 .. 5119]  W4 pairs in k3 arrangement: [lane l][s][di] = (W4[k3(g,2di,s)],W4[k3(g,2di+1,s)])
__global__ void prep_kernel(const float* __restrict__ W1, const float* __restrict__ b1,
                            const float* __restrict__ W2, const float* __restrict__ W3,
                            const float* __restrict__ W4, uint32_t* __restrict__ ws) {
  const int t = threadIdx.x;  // 256 threads, 1 block
  float* P1 = (float*)ws;
  if (t < 64) {
    P1[t * 8 + 0] = W1[0 * 64 + t];
    P1[t * 8 + 1] = W1[1 * 64 + t];
    P1[t * 8 + 2] = W1[2 * 64 + t];
    P1[t * 8 + 3] = W1[3 * 64 + t];
    P1[t * 8 + 4] = b1[t];
    P1[t * 8 + 5] = 0.f; P1[t * 8 + 6] = 0.f; P1[t * 8 + 7] = 0.f;
  }
  for (int idx = t; idx < 2048; idx += 256) {
    const int fi = idx >> 8;            // frag index 0..7 = tm*2 + s
    const int tm = fi >> 1, s = fi & 1;
    const int l  = (idx >> 2) & 63;     // lane
    const int pj = idx & 3;             // dword: halves j0=2pj, j0+1
    const int g  = l >> 4;
    const int mm = 16 * tm + (l & 15);  // h_out row
    const int j0 = 2 * pj, j1 = 2 * pj + 1;
    const int k2a = 16 * g + 8 * s + j0;
    const int k2b = 16 * g + 8 * s + j1;
    HU a; a.h[0] = (_Float16)W2[k2a * 64 + mm]; a.h[1] = (_Float16)W2[k2b * 64 + mm];
    ws[512 + idx] = a.u;
    const int k3a = 32 * s + 16 * (j0 >> 2) + 4 * g + (j0 & 3);
    const int k3b = 32 * s + 16 * (j1 >> 2) + 4 * g + (j1 & 3);
    HU b; b.h[0] = (_Float16)W3[k3a * 64 + mm]; b.h[1] = (_Float16)W3[k3b * 64 + mm];
    ws[2560 + idx] = b.u;
  }
  for (int t2 = t; t2 < 512; t2 += 256) {
    const int lq = t2 >> 3;             // lane
    const int s  = (t2 >> 2) & 1;
    const int di = t2 & 3;
    const int g  = lq >> 4;
    const int j0 = 2 * di, j1 = 2 * di + 1;
    const int h0 = 32 * s + 16 * (j0 >> 2) + 4 * g + (j0 & 3);
    const int h1 = 32 * s + 16 * (j1 >> 2) + 4 * g + (j1 & 3);
    HU a; a.h[0] = (_Float16)W4[h0]; a.h[1] = (_Float16)W4[h1];
    ws[4608 + t2] = a.u;
  }
}

#define MFMA16(A, B, C) __builtin_amdgcn_mfma_f32_16x16x32_f16((A), (B), (C), 0, 0, 0)

__global__ __launch_bounds__(256, 3)
void beam_kernel(const float* __restrict__ X, const float* __restrict__ Ein,
                 const float* __restrict__ Iin, const float* __restrict__ Qin,
                 const float* __restrict__ b2, const float* __restrict__ b3,
                 const float* __restrict__ b4, const uint32_t* __restrict__ ws,
                 float* __restrict__ out, int n) {
  const int tid = threadIdx.x;
  const int w   = tid >> 6;
  const int l   = tid & 63;
  const int g   = l >> 4;
  const int p   = l & 15;
  int i = (blockIdx.x * 4 + w) * 16 + p;
  if (i >= n) i = n - 1;

  const float x  = X[i];
  const float Ev = Ein[i], Iv = Iin[i], qv = Qin[i];
  const float f1 = Ev * 5.0e-12f;   // E / 2e11
  const float f2 = Iv * 1.0e6f;     // I / 1e-6
  const float f3 = qv * 1.0e-3f;    // q / 1e3
  const float sf = qv * fast_rcp(fmaf(Ev, Iv, 1.1920929e-7f));  // q/(E*I+eps)

  const float* P1f = (const float*)ws;

  // ---- Layer 1: jets for h = 16g + 2hp(+1), packed straight into B-frags
  //      (slot map = k2: slot (s, j=2di..) carries h = 16g + 8s + j) ----
  B128 bf[5][2];
  #pragma unroll
  for (int hp = 0; hp < 8; ++hp) {
    const int s = hp >> 2, di = hp & 3;
    const int h0 = 16 * g + 2 * hp;
    float A0, A1, A2, A3, A4, B0, B1, B2, B3, B4;
    {
      const float4 wv = *(const float4*)(P1f + h0 * 8);
      const float bb  = P1f[h0 * 8 + 4];
      float u0 = fmaf(wv.x, x, fmaf(wv.y, f1, fmaf(wv.z, f2, fmaf(wv.w, f3, bb))));
      tanh_jets(u0, wv.x, 0.f, 0.f, 0.f, A0, A1, A2, A3, A4);
    }
    {
      const float4 wv = *(const float4*)(P1f + (h0 + 1) * 8);
      const float bb  = P1f[(h0 + 1) * 8 + 4];
      float u0 = fmaf(wv.x, x, fmaf(wv.y, f1, fmaf(wv.z, f2, fmaf(wv.w, f3, bb))));
      tanh_jets(u0, wv.x, 0.f, 0.f, 0.f, B0, B1, B2, B3, B4);
    }
    bf[0][s].d[di] = pkrtz(A0, B0);
    bf[1][s].d[di] = pkrtz(A1, B1);
    bf[2][s].d[di] = pkrtz(A2, B2);
    bf[3][s].d[di] = pkrtz(A3, B3);
    bf[4][s].d[di] = pkrtz(A4, B4);
  }

  // ---- Layers 2 & 3: one shared code path, run twice (weights/bias differ).
  //      MFMA C map: col = p, row h_out = 16tm + 4g + r.
  //      Pack map (both iterations): slot (s = tm>>1, j = 4(tm&1)+r) = h_out,
  //      which equals k3(g,j,s) — matching the L3 weights and the L4 W4 pack. ----
  #pragma unroll 1
  for (int it = 0; it < 2; ++it) {
    const uint32_t* frags = ws + 512 + it * 2048;
    const float*    bias  = it ? b3 : b2;

    f32x4 acc[5][4];
    #pragma unroll
    for (int tm = 0; tm < 4; ++tm) {
      const float4 bv = *(const float4*)(bias + 16 * tm + 4 * g);
      acc[0][tm] = (f32x4){bv.x, bv.y, bv.z, bv.w};
      #pragma unroll
      for (int k = 1; k < 5; ++k) acc[k][tm] = (f32x4){0.f, 0.f, 0.f, 0.f};
    }
    #pragma unroll
    for (int s = 0; s < 2; ++s) {
      #pragma unroll
      for (int tm = 0; tm < 4; ++tm) {
        B128 af; af.q = *(const u128a*)(frags + ((tm * 2 + s) * 64 + l) * 4);
        #pragma unroll
        for (int k = 0; k < 5; ++k)
          acc[k][tm] = MFMA16(af.v, bf[k][s].v, acc[k][tm]);
      }
    }
    #pragma unroll
    for (int tm = 0; tm < 4; ++tm) {
      const int s = tm >> 1, db = 2 * (tm & 1);
      float A0, A1, A2, A3, A4, B0, B1, B2, B3, B4;
      tanh_jets(acc[0][tm][0], acc[1][tm][0], acc[2][tm][0], acc[3][tm][0], acc[4][tm][0],
                A0, A1, A2, A3, A4);
      tanh_jets(acc[0][tm][1], acc[1][tm][1], acc[2][tm][1], acc[3][tm][1], acc[4][tm][1],
                B0, B1, B2, B3, B4);
      bf[0][s].d[db] = pkrtz(A0, B0);
      bf[1][s].d[db] = pkrtz(A1, B1);
      bf[2][s].d[db] = pkrtz(A2, B2);
      bf[3][s].d[db] = pkrtz(A3, B3);
      bf[4][s].d[db] = pkrtz(A4, B4);
      tanh_jets(acc[0][tm][2], acc[1][tm][2], acc[2][tm][2], acc[3][tm][2], acc[4][tm][2],
                A0, A1, A2, A3, A4);
      tanh_jets(acc[0][tm][3], acc[1][tm][3], acc[2][tm][3], acc[3][tm][3], acc[4][tm][3],
                B0, B1, B2, B3, B4);
      bf[0][s].d[db + 1] = pkrtz(A0, B0);
      bf[1][s].d[db + 1] = pkrtz(A1, B1);
      bf[2][s].d[db + 1] = pkrtz(A2, B2);
      bf[3][s].d[db + 1] = pkrtz(A3, B3);
      bf[4][s].d[db + 1] = pkrtz(A4, B4);
    }
  }

  // ---- Layer 4 (64 -> 1): dot2 of packed activations with k3-packed W4,
  //      then butterfly-reduce across the 4 lanes sharing point p ----
  float zz[5] = {0.f, 0.f, 0.f, 0.f, 0.f};
  #pragma unroll
  for (int s = 0; s < 2; ++s) {
    B128 wq; wq.q = *(const u128a*)(ws + 4608 + l * 8 + s * 4);
    #pragma unroll
    for (int k = 0; k < 5; ++k) {
      #pragma unroll
      for (int di = 0; di < 4; ++di)
        zz[k] = fdot2f(bf[k][s].p2[di], wq.p2[di], zz[k]);
    }
  }
  #pragma unroll
  for (int k = 0; k < 5; ++k) {
    zz[k] += __shfl_xor(zz[k], 16, 64);
    zz[k] += __shfl_xor(zz[k], 32, 64);
  }

  if (l < 16) {
    const float psi   = zz[0] + b4[0];
    const float px    = zz[1];
    const float pxx   = 2.0f  * zz[2];
    const float pxxx  = 6.0f  * zz[3];
    const float pxxxx = 24.0f * zz[4];
    const float x2 = x * x;
    out[0 * n + i] = sf * (x2 * psi);
    out[1 * n + i] = sf * fmaf(2.0f * x, psi, x2 * px);
    out[2 * n + i] = sf * (fmaf(4.0f * x, px, 2.0f * psi) + x2 * pxx);
    out[3 * n + i] = sf * (fmaf(6.0f * x, pxx, 6.0f * px) + x2 * pxxx);
    out[4 * n + i] = sf * (fmaf(8.0f * x, pxxx, 12.0f * pxx) + x2 * pxxxx);
  }
}

extern "C" void kernel_launch(void* const* d_in, const int* in_sizes, int n_in,
                              void* d_out, int out_size, void* d_ws, size_t ws_size,
                              hipStream_t stream) {
  const float* X  = (const float*)d_in[0];
  const float* E  = (const float*)d_in[1];
  const float* I  = (const float*)d_in[2];
  const float* q  = (const float*)d_in[3];
  const float* W1 = (const float*)d_in[4];
  const float* b1 = (const float*)d_in[5];
  const float* W2 = (const float*)d_in[6];
  const float* b2 = (const float*)d_in[7];
  const float* W3 = (const float*)d_in[8];
  const float* b3 = (const float*)d_in[9];
  const float* W4 = (const float*)d_in[10];
  const float* b4 = (const float*)d_in[11];
  const int n = in_sizes[0];
  uint32_t* ws = (uint32_t*)d_ws;
  float* out = (float*)d_out;

  prep_kernel<<<dim3(1), dim3(256), 0, stream>>>(W1, b1, W2, W3, W4, ws);
  // block = 256 threads = 4 waves; each wave = 16 points -> 64 points/block
  beam_kernel<<<dim3((n + 63) / 64), dim3(256), 0, stream>>>(X, E, I, q, b2, b3, b4, ws, out, n);
}